// Round 2
// baseline (781.839 us; speedup 1.0000x reference)
//
#include <hip/hip_runtime.h>
#include <hip/hip_bf16.h>

#define NTOK 511
#define NINT 255

typedef unsigned short u16;

// ---- workspace layout (float offsets) ----
constexpr int OFF_FLAG = 0;                    // [0] dtype flag (int): 1=bf16, 0=fp32
constexpr int OFF_WP   = 4;                    // Wpack  [128][128][4]  = 65536
constexpr int OFF_UB4  = OFF_WP  + 65536;      // Ub4    [256][128][4]  = 131072
constexpr int OFF_UB1  = OFF_UB4 + 131072;     // Ub1    [256][128]     = 32768
constexpr int OFF_UU4  = OFF_UB1 + 32768;      // Uu4    [128][128][4]  = 65536
constexpr int OFF_W3   = OFF_UU4 + 65536;      // W3p    [128][128]     = 16384
constexpr int OFF_BW   = OFF_W3  + 16384;      // bW     [128][4]
constexpr int OFF_BUB4 = OFF_BW  + 512;        // bUbin g0..3 [128][4]
constexpr int OFF_BUB1 = OFF_BUB4 + 512;       // bUbin g4    [128]
constexpr int OFF_BUU4 = OFF_BUB1 + 128;       // bUun  [128][4]
constexpr int OFF_BW3  = OFF_BUU4 + 512;       // bW[3] [128]
constexpr int OFF_ROOT = OFF_BW3 + 128;        // rootH [256][128] + rootC [256][128]
constexpr int OFF_CHUNK= OFF_ROOT + 65536;     // per-chunk ping-pong region
// per-tree chunk floats: Ha 256*128 + Hb 128*128 + Ca 64*128 + Cb 128*128
constexpr long PER_TREE = 32768 + 16384 + 8192 + 16384;   // 73728 floats = 288 KB

__device__ __forceinline__ float bf2f(__hip_bfloat16 v) { return __bfloat162float(v); }
__device__ __forceinline__ float sigm(float x) { return 1.0f / (1.0f + __expf(-x)); }
__device__ __forceinline__ float tanh_(float x) { return 1.0f - 2.0f / (__expf(2.0f * x) + 1.0f); }

__device__ __forceinline__ void unpack8(uint4 v, float* dst) {
    dst[0] = __uint_as_float(v.x << 16); dst[1] = __uint_as_float(v.x & 0xffff0000u);
    dst[2] = __uint_as_float(v.y << 16); dst[3] = __uint_as_float(v.y & 0xffff0000u);
    dst[4] = __uint_as_float(v.z << 16); dst[5] = __uint_as_float(v.z & 0xffff0000u);
    dst[6] = __uint_as_float(v.w << 16); dst[7] = __uint_as_float(v.w & 0xffff0000u);
}

// dual-dtype scalar load of logical element idx
__device__ __forceinline__ float ldf(const void* p, long idx, int isbf) {
    return isbf ? bf2f(((const __hip_bfloat16*)p)[idx]) : ((const float*)p)[idx];
}

// dual-dtype 8-element row-chunk load into LDS (dst 16B-aligned, src element idx 8-aligned)
__device__ __forceinline__ void ld8(const void* p, long idx, int isbf, float* dst) {
    if (isbf) {
        uint4 v = *(const uint4*)((const __hip_bfloat16*)p + idx);
        unpack8(v, dst);
    } else {
        const float* f = (const float*)p + idx;
        *(float4*)dst       = *(const float4*)f;
        *(float4*)(dst + 4) = *(const float4*)(f + 4);
    }
}

// ---- dtype detection: fp32 little-endian data has random low uint16s; bf16 has
// all-plausible exponent fields. Vote on 64 even-index uint16s of W. ----
__global__ void detect_kernel(const void* W, float* ws) {
    if (threadIdx.x == 0 && blockIdx.x == 0) {
        const u16* u = (const u16*)W;
        int cnt = 0;
        for (int i = 0; i < 128; i += 2) {
            u16 x = u[i];
            int ex = (x >> 7) & 0xff;
            if (x == 0 || (ex >= 96 && ex <= 127)) cnt++;
        }
        ((int*)ws)[0] = (cnt >= 48) ? 1 : 0;
    }
}

// ---- weight repack: raw (bf16 or fp32) gate-major -> fp32 gate-interleaved ----
__global__ __launch_bounds__(256) void repack_kernel(
    const void* W, const void* bW, const void* Ubin, const void* bUbin,
    const void* Uun, const void* bUun, float* ws)
{
    const int isbf = ((const int*)ws)[0];
    int tid = blockIdx.x * blockDim.x + threadIdx.x;
    int nth = gridDim.x * blockDim.x;
    for (int idx = tid; idx < 128 * 128; idx += nth) {
        int k = idx >> 7, j = idx & 127;
        float4 w;
        w.x = ldf(W, 0 * 16384 + k * 128 + j, isbf);
        w.y = ldf(W, 1 * 16384 + k * 128 + j, isbf);
        w.z = ldf(W, 2 * 16384 + k * 128 + j, isbf);
        w.w = ldf(W, 3 * 16384 + k * 128 + j, isbf);
        ((float4*)(ws + OFF_WP))[idx] = w;
        (ws + OFF_W3)[idx] = w.w;
        float4 u;
        u.x = ldf(Uun, 0 * 16384 + k * 128 + j, isbf);
        u.y = ldf(Uun, 1 * 16384 + k * 128 + j, isbf);
        u.z = ldf(Uun, 2 * 16384 + k * 128 + j, isbf);
        u.w = ldf(Uun, 3 * 16384 + k * 128 + j, isbf);
        ((float4*)(ws + OFF_UU4))[idx] = u;
    }
    for (int idx = tid; idx < 256 * 128; idx += nth) {
        int k = idx >> 7, j = idx & 127;
        float4 u;
        u.x = ldf(Ubin, 0 * 32768 + k * 128 + j, isbf);
        u.y = ldf(Ubin, 1 * 32768 + k * 128 + j, isbf);
        u.z = ldf(Ubin, 2 * 32768 + k * 128 + j, isbf);
        u.w = ldf(Ubin, 3 * 32768 + k * 128 + j, isbf);
        ((float4*)(ws + OFF_UB4))[idx] = u;
        (ws + OFF_UB1)[idx] = ldf(Ubin, 4 * 32768 + k * 128 + j, isbf);
    }
    for (int j = tid; j < 128; j += nth) {
        float4 b;
        b.x = ldf(bW, 0 * 128 + j, isbf); b.y = ldf(bW, 1 * 128 + j, isbf);
        b.z = ldf(bW, 2 * 128 + j, isbf); b.w = ldf(bW, 3 * 128 + j, isbf);
        ((float4*)(ws + OFF_BW))[j] = b;
        float4 bb;
        bb.x = ldf(bUbin, 0 * 128 + j, isbf); bb.y = ldf(bUbin, 1 * 128 + j, isbf);
        bb.z = ldf(bUbin, 2 * 128 + j, isbf); bb.w = ldf(bUbin, 3 * 128 + j, isbf);
        ((float4*)(ws + OFF_BUB4))[j] = bb;
        (ws + OFF_BUB1)[j] = ldf(bUbin, 4 * 128 + j, isbf);
        float4 bu;
        bu.x = ldf(bUun, 0 * 128 + j, isbf); bu.y = ldf(bUun, 1 * 128 + j, isbf);
        bu.z = ldf(bUun, 2 * 128 + j, isbf); bu.w = ldf(bUun, 3 * 128 + j, isbf);
        ((float4*)(ws + OFF_BUU4))[j] = bu;
        (ws + OFF_BW3)[j] = ldf(bW, 3 * 128 + j, isbf);
    }
}

// ---- leaf kernel: h = tanh(emb[tok] @ W3 + bW3); 64 leaves/block, chunk-local ----
__global__ __launch_bounds__(256) void leaf_kernel(
    const int* __restrict__ tokens, const void* emb, const float* ws,
    float* __restrict__ hOut, int treeOff)
{
    __shared__ float e[64 * 128];
    __shared__ int tok[64];
    const int t = threadIdx.x;
    const int p0 = blockIdx.x * 64;
    const int isbf = ((const int*)ws)[0];

    if (t < 64) {
        int p = p0 + t; int bl = p >> 8; int i = p & 255;
        tok[t] = tokens[(long)(treeOff + bl) * NTOK + 255 + i];
    }
    __syncthreads();
    for (int r = 0; r < 4; ++r) {
        int q = r * 256 + t; int m = q >> 4, ch = q & 15;
        ld8(emb, (long)tok[m] * 128 + ch * 8, isbf, &e[m * 128 + ch * 8]);
    }
    __syncthreads();

    const int jslot = t & 31, j = jslot * 4, mbase = (t >> 5) * 8;
    const float* W3 = ws + OFF_W3;
    float acc[8][4];
#pragma unroll
    for (int mm = 0; mm < 8; ++mm) { acc[mm][0] = acc[mm][1] = acc[mm][2] = acc[mm][3] = 0.f; }

    for (int k = 0; k < 128; k += 4) {
        float4 w0 = *(const float4*)&W3[(k + 0) * 128 + j];
        float4 w1 = *(const float4*)&W3[(k + 1) * 128 + j];
        float4 w2 = *(const float4*)&W3[(k + 2) * 128 + j];
        float4 w3 = *(const float4*)&W3[(k + 3) * 128 + j];
#pragma unroll
        for (int mm = 0; mm < 8; ++mm) {
            float4 ev = *(const float4*)&e[(mbase + mm) * 128 + k];
            acc[mm][0] += ev.x * w0.x + ev.y * w1.x + ev.z * w2.x + ev.w * w3.x;
            acc[mm][1] += ev.x * w0.y + ev.y * w1.y + ev.z * w2.y + ev.w * w3.y;
            acc[mm][2] += ev.x * w0.z + ev.y * w1.z + ev.z * w2.z + ev.w * w3.z;
            acc[mm][3] += ev.x * w0.w + ev.y * w1.w + ev.z * w2.w + ev.w * w3.w;
        }
    }
    float4 b3 = *(const float4*)&ws[OFF_BW3 + j];
#pragma unroll
    for (int mm = 0; mm < 8; ++mm) {
        int p = p0 + mbase + mm;                 // chunk-local leaf index
        float4 hv;
        hv.x = tanh_(acc[mm][0] + b3.x);
        hv.y = tanh_(acc[mm][1] + b3.y);
        hv.z = tanh_(acc[mm][2] + b3.z);
        hv.w = tanh_(acc[mm][3] + b3.w);
        *(float4*)&hOut[(long)p * 128 + j] = hv;  // [bl*256+i][128]
    }
}

// ---- internal-level kernel, chunk-local ping-pong buffers ----
template <int TM>
__global__ __launch_bounds__(256) void level_kernel(
    const int* __restrict__ tokens, const int* __restrict__ arity, const void* emb,
    const float* ws, const float* __restrict__ hChild, const float* __restrict__ cChild,
    float* __restrict__ hOut, float* __restrict__ cOut,
    int lvl, int treeOff, int leafchild)
{
    constexpr int NPG = TM / 2;
    const int cnt = 1 << lvl, o2 = cnt - 1, ccnt = cnt << 1;
    __shared__ float e[TM * 128];
    __shared__ float hc[TM * 256];
    __shared__ int tok[TM];
    __shared__ int ar[TM];

    const int t = threadIdx.x;
    const int p0 = blockIdx.x * TM;
    const int isbf = ((const int*)ws)[0];

    if (t < TM) {
        int p = p0 + t; int bl = p >> lvl; int i = p - (bl << lvl);
        tok[t] = tokens[(long)(treeOff + bl) * NTOK + o2 + i];
        ar[t]  = arity[(long)(treeOff + bl) * NINT + o2 + i];
    }
    __syncthreads();
    for (int q = t; q < TM * 16; q += 256) {
        int m = q >> 4, ch = q & 15;
        ld8(emb, (long)tok[m] * 128 + ch * 8, isbf, &e[m * 128 + ch * 8]);
    }
    for (int q = t; q < TM * 64; q += 256) {
        int m = q >> 6; int half = (q >> 5) & 1; int e4 = q & 31;
        int p = p0 + m; int bl = p >> lvl; int i = p - (bl << lvl);
        int ci = 2 * i + half;
        float4 hv = *(const float4*)&hChild[((long)bl * ccnt + ci) * 128 + e4 * 4];
        *(float4*)&hc[m * 256 + half * 128 + e4 * 4] = hv;
    }
    __syncthreads();

    const int jj = t & 127;
    const int mbase = (t >> 7) * NPG;

    bool bin[NPG];
#pragma unroll
    for (int mm = 0; mm < NPG; ++mm) bin[mm] = (ar[mbase + mm] == 1);

    float accW[NPG][4];
    float accR[NPG][5];
#pragma unroll
    for (int mm = 0; mm < NPG; ++mm) {
        accW[mm][0] = accW[mm][1] = accW[mm][2] = accW[mm][3] = 0.f;
        accR[mm][0] = accR[mm][1] = accR[mm][2] = accR[mm][3] = accR[mm][4] = 0.f;
    }

    // Phase A: Wx, K=128
    {
        const float4* Wp = (const float4*)(ws + OFF_WP);
        for (int k = 0; k < 128; k += 4) {
            float4 w0 = Wp[(k + 0) * 128 + jj];
            float4 w1 = Wp[(k + 1) * 128 + jj];
            float4 w2 = Wp[(k + 2) * 128 + jj];
            float4 w3 = Wp[(k + 3) * 128 + jj];
#pragma unroll
            for (int mm = 0; mm < NPG; ++mm) {
                float4 ev = *(const float4*)&e[(mbase + mm) * 128 + k];
                accW[mm][0] += ev.x * w0.x + ev.y * w1.x + ev.z * w2.x + ev.w * w3.x;
                accW[mm][1] += ev.x * w0.y + ev.y * w1.y + ev.z * w2.y + ev.w * w3.y;
                accW[mm][2] += ev.x * w0.z + ev.y * w1.z + ev.z * w2.z + ev.w * w3.z;
                accW[mm][3] += ev.x * w0.w + ev.y * w1.w + ev.z * w2.w + ev.w * w3.w;
            }
        }
    }
    // Phase B: Ub (binary nodes), K=256 over hcat — wave-uniform skip per node group
    {
        const float4* U4 = (const float4*)(ws + OFF_UB4);
        const float*  U1 = ws + OFF_UB1;
        for (int k = 0; k < 256; k += 4) {
            float4 u0 = U4[(k + 0) * 128 + jj];
            float4 u1 = U4[(k + 1) * 128 + jj];
            float4 u2 = U4[(k + 2) * 128 + jj];
            float4 u3 = U4[(k + 3) * 128 + jj];
            float s0 = U1[(k + 0) * 128 + jj];
            float s1 = U1[(k + 1) * 128 + jj];
            float s2 = U1[(k + 2) * 128 + jj];
            float s3 = U1[(k + 3) * 128 + jj];
#pragma unroll
            for (int mm = 0; mm < NPG; ++mm) {
                if (bin[mm]) {
                    float4 hv = *(const float4*)&hc[(mbase + mm) * 256 + k];
                    accR[mm][0] += hv.x * u0.x + hv.y * u1.x + hv.z * u2.x + hv.w * u3.x;
                    accR[mm][1] += hv.x * u0.y + hv.y * u1.y + hv.z * u2.y + hv.w * u3.y;
                    accR[mm][2] += hv.x * u0.z + hv.y * u1.z + hv.z * u2.z + hv.w * u3.z;
                    accR[mm][3] += hv.x * u0.w + hv.y * u1.w + hv.z * u2.w + hv.w * u3.w;
                    accR[mm][4] += hv.x * s0 + hv.y * s1 + hv.z * s2 + hv.w * s3;
                }
            }
        }
    }
    // Phase C: Uu (unary nodes), K=128 over h_l
    {
        const float4* U4 = (const float4*)(ws + OFF_UU4);
        for (int k = 0; k < 128; k += 4) {
            float4 u0 = U4[(k + 0) * 128 + jj];
            float4 u1 = U4[(k + 1) * 128 + jj];
            float4 u2 = U4[(k + 2) * 128 + jj];
            float4 u3 = U4[(k + 3) * 128 + jj];
#pragma unroll
            for (int mm = 0; mm < NPG; ++mm) {
                if (!bin[mm]) {
                    float4 hv = *(const float4*)&hc[(mbase + mm) * 256 + k];
                    accR[mm][0] += hv.x * u0.x + hv.y * u1.x + hv.z * u2.x + hv.w * u3.x;
                    accR[mm][1] += hv.x * u0.y + hv.y * u1.y + hv.z * u2.y + hv.w * u3.y;
                    accR[mm][2] += hv.x * u0.z + hv.y * u1.z + hv.z * u2.z + hv.w * u3.z;
                    accR[mm][3] += hv.x * u0.w + hv.y * u1.w + hv.z * u2.w + hv.w * u3.w;
                }
            }
        }
    }

    // Epilogue
    float4 bw  = ((const float4*)(ws + OFF_BW))[jj];
    float4 bub = ((const float4*)(ws + OFF_BUB4))[jj];
    float  bub1 = (ws + OFF_BUB1)[jj];
    float4 buu = ((const float4*)(ws + OFF_BUU4))[jj];
#pragma unroll
    for (int mm = 0; mm < NPG; ++mm) {
        int p = p0 + mbase + mm; int bl = p >> lvl; int i = p - (bl << lvl);
        float wx0 = accW[mm][0] + bw.x;
        float wx1 = accW[mm][1] + bw.y;
        float wx2 = accW[mm][2] + bw.z;
        float wx3 = accW[mm][3] + bw.w;
        float h, c;
        float cl = leafchild ? 0.f : cChild[((long)bl * ccnt + 2 * i) * 128 + jj];
        if (bin[mm]) {
            float cr = leafchild ? 0.f : cChild[((long)bl * ccnt + 2 * i + 1) * 128 + jj];
            float ig = sigm(wx0 + accR[mm][0] + bub.x);
            float fl = sigm(wx1 + accR[mm][1] + bub.y);
            float fr = sigm(wx1 + accR[mm][2] + bub.z);
            float og = sigm(wx2 + accR[mm][3] + bub.w);
            float ug = tanh_(wx3 + accR[mm][4] + bub1);
            c = ig * ug + fl * cl + fr * cr;
            h = og * tanh_(c);
        } else {
            float ig = sigm(wx0 + accR[mm][0] + buu.x);
            float fu = sigm(wx1 + accR[mm][1] + buu.y);
            float og = sigm(wx2 + accR[mm][2] + buu.z);
            float uu = tanh_(wx3 + accR[mm][3] + buu.w);
            c = ig * uu + fu * cl;
            h = og * tanh_(c);
        }
        hOut[((long)bl * cnt + i) * 128 + jj] = h;
        cOut[((long)bl * cnt + i) * 128 + jj] = c;
    }
}

// ---- output: root h, c (fp32) -> d_out (bf16 or fp32 per flag) ----
__global__ __launch_bounds__(256) void out_kernel(const float* ws, void* out)
{
    const int isbf = ((const int*)ws)[0];
    const float* rootH = ws + OFF_ROOT;
    const float* rootC = rootH + 32768;
    int t = blockIdx.x * 256 + threadIdx.x;   // 32768 threads
    float h = rootH[t], c = rootC[t];
    if (isbf) {
        ((__hip_bfloat16*)out)[t]         = __float2bfloat16(h);
        ((__hip_bfloat16*)out)[32768 + t] = __float2bfloat16(c);
    } else {
        ((float*)out)[t]         = h;
        ((float*)out)[32768 + t] = c;
    }
}

extern "C" void kernel_launch(void* const* d_in, const int* in_sizes, int n_in,
                              void* d_out, int out_size, void* d_ws, size_t ws_size,
                              hipStream_t stream)
{
    const int* tokens = (const int*)d_in[0];
    const int* arity  = (const int*)d_in[1];
    const void* emb   = d_in[2];
    const void* W     = d_in[3];
    const void* bW    = d_in[4];
    const void* Ubin  = d_in[5];
    const void* bUbin = d_in[6];
    const void* Uun   = d_in[7];
    const void* bUun  = d_in[8];

    float* ws = (float*)d_ws;

    // largest power-of-2 chunk of trees that fits in ws
    int Bc = 256;
    while (Bc > 2 && (size_t)(OFF_CHUNK + (long)Bc * PER_TREE) * 4 > ws_size) Bc >>= 1;
    const int nCh = 256 / Bc;

    detect_kernel<<<1, 64, 0, stream>>>(W, ws);
    repack_kernel<<<128, 256, 0, stream>>>(W, bW, Ubin, bUbin, Uun, bUun, ws);

    float* Ha = ws + OFF_CHUNK;                 // leaf h / even-level h
    float* Hb = Ha + (long)Bc * 32768;          // odd-level h
    float* Ca = Hb + (long)Bc * 16384;          // even-level c
    float* Cb = Ca + (long)Bc * 8192;           // odd-level c
    float* rootH = ws + OFF_ROOT;
    float* rootC = rootH + 32768;

    for (int cidx = 0; cidx < nCh; ++cidx) {
        int toff = cidx * Bc;
        leaf_kernel<<<Bc * 4, 256, 0, stream>>>(tokens, emb, ws, Ha, toff);
        for (int l = 7; l >= 0; --l) {
            int M = Bc << l;
            bool even = ((l & 1) == 0);
            const float* hC = (l == 7) ? Ha : (even ? Hb : Ha);
            const float* cC = (l == 7) ? nullptr : (even ? Cb : Ca);
            float* hO = even ? Ha : Hb;
            float* cO = even ? Ca : Cb;
            if (l == 0) { hO = rootH + (long)toff * 128; cO = rootC + (long)toff * 128; }
            int lc = (l == 7) ? 1 : 0;
            if (l >= 4)
                level_kernel<16><<<M / 16, 256, 0, stream>>>(tokens, arity, emb, ws, hC, cC, hO, cO, l, toff, lc);
            else if (l == 3)
                level_kernel<8><<<M / 8, 256, 0, stream>>>(tokens, arity, emb, ws, hC, cC, hO, cO, l, toff, lc);
            else
                level_kernel<2><<<M / 2, 256, 0, stream>>>(tokens, arity, emb, ws, hC, cC, hO, cO, l, toff, lc);
        }
    }
    out_kernel<<<128, 256, 0, stream>>>(ws, d_out);
}

// Round 3
// 527.110 us; speedup vs baseline: 1.4833x; 1.4833x over previous
//
#include <hip/hip_runtime.h>
#include <hip/hip_bf16.h>

#define NTOK 511
#define NINT 255

typedef unsigned short u16;
typedef __attribute__((ext_vector_type(8))) short bf16x8;
typedef __attribute__((ext_vector_type(4))) float f32x4;

// ---- workspace layout (float offsets) ----
constexpr int OFF_FLAG = 0;                 // [0] dtype flag
constexpr int OFF_WB   = 4;                 // bf16 weight region (B-fragment-linear)
// bf16-element offsets inside weight region:
constexpr int WXB = 0;                      // 4g x 8jc x 4ks x 512 = 65536
constexpr int UBB = 65536;                  // 5g x 8jc x 8ks x 512 = 163840
constexpr int UUB = 229376;                 // 4g x 8jc x 4ks x 512 = 65536
constexpr int W3B = 294912;                 // 8jc x 4ks x 512      = 16384
constexpr int WB_ELEMS = 311296;            // = 155648 floats
constexpr int OFF_BIAS = OFF_WB + WB_ELEMS / 2;   // 155652 (16B aligned)
constexpr int BW4 = 0, BUB4 = 512, BUB1 = 1024, BUU4 = 1152, B3 = 1664;
constexpr int BIAS_FLOATS = 1792;
constexpr int OFF_ROOT  = OFF_BIAS + BIAS_FLOATS;   // rootH 32768 + rootC 32768 (fp32)
constexpr int OFF_CHUNK = OFF_ROOT + 65536;
// per-tree chunk bytes: Ha 256*128 bf16 + Hb 128*128 bf16 + Ca 64*128 f32 + Cb 128*128 f32
constexpr long PER_TREE = 49152;            // floats

__device__ __forceinline__ float bf2f(__hip_bfloat16 v) { return __bfloat162float(v); }
__device__ __forceinline__ short f2s(float f) {
    __hip_bfloat16 b = __float2bfloat16(f);
    return *reinterpret_cast<short*>(&b);
}
__device__ __forceinline__ float sigm(float x) { return 1.0f / (1.0f + __expf(-x)); }
__device__ __forceinline__ float tanh_(float x) { return 1.0f - 2.0f / (__expf(2.0f * x) + 1.0f); }

__device__ __forceinline__ float ldf(const void* p, long idx, int isbf) {
    return isbf ? bf2f(((const __hip_bfloat16*)p)[idx]) : ((const float*)p)[idx];
}

// ---- dtype detection (fp32 halves look random; bf16 exponents plausible) ----
__global__ void detect_kernel(const void* W, float* ws) {
    if (threadIdx.x == 0 && blockIdx.x == 0) {
        const u16* u = (const u16*)W;
        int cnt = 0;
        for (int i = 0; i < 128; i += 2) {
            u16 x = u[i];
            int ex = (x >> 7) & 0xff;
            if (x == 0 || (ex >= 96 && ex <= 127)) cnt++;
        }
        ((int*)ws)[0] = (cnt >= 48) ? 1 : 0;
    }
}

// ---- repack: raw weights -> bf16 B-fragment-linear + fp32 biases ----
__global__ __launch_bounds__(256) void repack_mfma(
    const void* W, const void* bW, const void* Ubin, const void* bUbin,
    const void* Uun, const void* bUun, float* ws)
{
    const int isbf = ((const int*)ws)[0];
    short* wb = (short*)(ws + OFF_WB);
    float* bias = ws + OFF_BIAS;
    int tid = blockIdx.x * blockDim.x + threadIdx.x;
    int nth = gridDim.x * blockDim.x;

    for (int idx = tid; idx < 65536; idx += nth) {
        int frag = idx >> 9, e = idx & 511;
        int lane = e >> 3, id8 = e & 7;
        int g = frag >> 5, jc = (frag >> 2) & 7, ks = frag & 3;
        int k = ks * 32 + (lane >> 4) * 8 + id8;
        int jg = jc * 16 + (lane & 15);
        wb[WXB + idx] = f2s(ldf(W,   (long)g * 16384 + k * 128 + jg, isbf));
        wb[UUB + idx] = f2s(ldf(Uun, (long)g * 16384 + k * 128 + jg, isbf));
    }
    for (int idx = tid; idx < 163840; idx += nth) {
        int frag = idx >> 9, e = idx & 511;
        int lane = e >> 3, id8 = e & 7;
        int g = frag >> 6, rem = frag & 63, jc = rem >> 3, ks = rem & 7;
        int k = ks * 32 + (lane >> 4) * 8 + id8;
        int jg = jc * 16 + (lane & 15);
        wb[UBB + idx] = f2s(ldf(Ubin, (long)g * 32768 + k * 128 + jg, isbf));
    }
    for (int idx = tid; idx < 16384; idx += nth) {
        int frag = idx >> 9, e = idx & 511;
        int lane = e >> 3, id8 = e & 7;
        int jc = frag >> 2, ks = frag & 3;
        int k = ks * 32 + (lane >> 4) * 8 + id8;
        int jg = jc * 16 + (lane & 15);
        wb[W3B + idx] = f2s(ldf(W, (long)3 * 16384 + k * 128 + jg, isbf));
    }
    for (int j = tid; j < 128; j += nth) {
        float4 b;
        b.x = ldf(bW, 0 * 128 + j, isbf); b.y = ldf(bW, 1 * 128 + j, isbf);
        b.z = ldf(bW, 2 * 128 + j, isbf); b.w = ldf(bW, 3 * 128 + j, isbf);
        ((float4*)(bias + BW4))[j] = b;
        float4 bb;
        bb.x = ldf(bUbin, 0 * 128 + j, isbf); bb.y = ldf(bUbin, 1 * 128 + j, isbf);
        bb.z = ldf(bUbin, 2 * 128 + j, isbf); bb.w = ldf(bUbin, 3 * 128 + j, isbf);
        ((float4*)(bias + BUB4))[j] = bb;
        (bias + BUB1)[j] = ldf(bUbin, 4 * 128 + j, isbf);
        float4 bu;
        bu.x = ldf(bUun, 0 * 128 + j, isbf); bu.y = ldf(bUun, 1 * 128 + j, isbf);
        bu.z = ldf(bUun, 2 * 128 + j, isbf); bu.w = ldf(bUun, 3 * 128 + j, isbf);
        ((float4*)(bias + BUU4))[j] = bu;
        (bias + B3)[j] = ldf(bW, 3 * 128 + j, isbf);
    }
}

#define MFMA(A, B, C) __builtin_amdgcn_mfma_f32_16x16x32_bf16(A, B, C, 0, 0, 0)

// ---- leaf: h = tanh(x @ W3 + b3), 64 leaves/block ----
__global__ __launch_bounds__(256) void leaf_mfma(
    const int* __restrict__ tokens, const void* emb, const float* __restrict__ ws,
    short* __restrict__ hOut, int treeOff)
{
    __shared__ short xs[64][136];
    __shared__ int tok[64];
    const int t = threadIdx.x;
    const int isbf = ((const int*)ws)[0];
    const int p0 = blockIdx.x * 64;

    if (t < 64) {
        int p = p0 + t; int bl = p >> 8; int i = p & 255;
        tok[t] = tokens[(long)(treeOff + bl) * NTOK + 255 + i];
    }
    __syncthreads();
    const short* eb = (const short*)emb;
    const float* ef = (const float*)emb;
    for (int q = t; q < 1024; q += 256) {
        int m = q >> 4, ch = q & 15;
        long src = (long)tok[m] * 128 + ch * 8;
        if (isbf) {
            *(uint4*)&xs[m][ch * 8] = *(const uint4*)(eb + src);
        } else {
            float4 a = *(const float4*)(ef + src);
            float4 b = *(const float4*)(ef + src + 4);
            short* d = &xs[m][ch * 8];
            d[0] = f2s(a.x); d[1] = f2s(a.y); d[2] = f2s(a.z); d[3] = f2s(a.w);
            d[4] = f2s(b.x); d[5] = f2s(b.y); d[6] = f2s(b.z); d[7] = f2s(b.w);
        }
    }
    __syncthreads();

    const int wv = t >> 6, lane = t & 63, quad = lane >> 4, l16 = lane & 15;
    const int mbase = (wv >> 1) * 32;
    const int jc0 = (wv & 1) * 4;
    const short* wb = (const short*)(ws + OFF_WB);
    const float* bias = ws + OFF_BIAS;

    for (int cix = 0; cix < 4; ++cix) {
        int jc = jc0 + cix;
        f32x4 acc0 = {0.f, 0.f, 0.f, 0.f}, acc1 = {0.f, 0.f, 0.f, 0.f};
#pragma unroll
        for (int ks = 0; ks < 4; ++ks) {
            bf16x8 a0 = *(const bf16x8*)&xs[mbase + l16][ks * 32 + quad * 8];
            bf16x8 a1 = *(const bf16x8*)&xs[mbase + 16 + l16][ks * 32 + quad * 8];
            bf16x8 b = *(const bf16x8*)(wb + W3B + ((jc * 4 + ks) << 9) + lane * 8);
            acc0 = MFMA(a0, b, acc0);
            acc1 = MFMA(a1, b, acc1);
        }
        int j = jc * 16 + l16;
        float b3v = (bias + B3)[j];
#pragma unroll
        for (int mt = 0; mt < 2; ++mt)
#pragma unroll
        for (int r = 0; r < 4; ++r) {
            float v = (mt == 0 ? acc0[r] : acc1[r]) + b3v;
            int p = p0 + mbase + mt * 16 + quad * 4 + r;
            hOut[(long)p * 128 + j] = f2s(tanh_(v));
        }
    }
}

// ---- internal level: dense both-path MFMA, 64 nodes/block ----
__global__ __launch_bounds__(256) void level_mfma(
    const int* __restrict__ tokens, const int* __restrict__ arity, const void* emb,
    const float* __restrict__ ws, const short* __restrict__ hChild,
    const float* __restrict__ cChild, short* __restrict__ hOut, float* __restrict__ cOut,
    float* __restrict__ rootH, float* __restrict__ rootC,
    int lvl, int treeOff, int leafchild, int isRoot, int Mtot)
{
    __shared__ short xs[64][136];
    __shared__ short hs[64][264];
    __shared__ int tok[64];
    __shared__ int ar[64];

    const int t = threadIdx.x;
    const int isbf = ((const int*)ws)[0];
    const int p0 = blockIdx.x * 64;
    const int cnt = 1 << lvl, ccnt = cnt << 1, o2 = cnt - 1;

    if (t < 64) {
        int p = p0 + t; if (p >= Mtot) p = Mtot - 1;
        int bl = p >> lvl, i = p - (bl << lvl);
        tok[t] = tokens[(long)(treeOff + bl) * NTOK + o2 + i];
        ar[t]  = arity[(long)(treeOff + bl) * NINT + o2 + i];
    }
    __syncthreads();

    const short* eb = (const short*)emb;
    const float* ef = (const float*)emb;
    for (int q = t; q < 1024; q += 256) {
        int m = q >> 4, ch = q & 15;
        long src = (long)tok[m] * 128 + ch * 8;
        if (isbf) {
            *(uint4*)&xs[m][ch * 8] = *(const uint4*)(eb + src);
        } else {
            float4 a = *(const float4*)(ef + src);
            float4 b = *(const float4*)(ef + src + 4);
            short* d = &xs[m][ch * 8];
            d[0] = f2s(a.x); d[1] = f2s(a.y); d[2] = f2s(a.z); d[3] = f2s(a.w);
            d[4] = f2s(b.x); d[5] = f2s(b.y); d[6] = f2s(b.z); d[7] = f2s(b.w);
        }
    }
    for (int q = t; q < 2048; q += 256) {
        int m = q >> 5, half = (q >> 4) & 1, ch = q & 15;
        int p = p0 + m; if (p >= Mtot) p = Mtot - 1;
        int bl = p >> lvl, i = p - (bl << lvl);
        long crow = (long)bl * ccnt + 2 * i + half;
        *(uint4*)&hs[m][half * 128 + ch * 8] = *(const uint4*)(hChild + crow * 128 + ch * 8);
    }
    __syncthreads();

    const int wv = t >> 6, lane = t & 63, quad = lane >> 4, l16 = lane & 15;
    const int mbase = (wv >> 1) * 32;
    const int jc0 = (wv & 1) * 4;
    const short* wb = (const short*)(ws + OFF_WB);
    const float* bias = ws + OFF_BIAS;

    for (int cix = 0; cix < 4; ++cix) {
        int jc = jc0 + cix;
        f32x4 aW[4][2], aB[5][2], aU[4][2];
#pragma unroll
        for (int g = 0; g < 4; ++g) { aW[g][0] = {0,0,0,0}; aW[g][1] = {0,0,0,0}; }
#pragma unroll
        for (int g = 0; g < 5; ++g) { aB[g][0] = {0,0,0,0}; aB[g][1] = {0,0,0,0}; }
#pragma unroll
        for (int g = 0; g < 4; ++g) { aU[g][0] = {0,0,0,0}; aU[g][1] = {0,0,0,0}; }

        // Phase Wx: A = x (K=128)
        {
            bf16x8 ax[2][4];
#pragma unroll
            for (int mt = 0; mt < 2; ++mt)
#pragma unroll
            for (int ks = 0; ks < 4; ++ks)
                ax[mt][ks] = *(const bf16x8*)&xs[mbase + mt * 16 + l16][ks * 32 + quad * 8];
#pragma unroll
            for (int g = 0; g < 4; ++g)
#pragma unroll
            for (int ks = 0; ks < 4; ++ks) {
                bf16x8 b = *(const bf16x8*)(wb + WXB + ((((g * 8 + jc) * 4) + ks) << 9) + lane * 8);
                aW[g][0] = MFMA(ax[0][ks], b, aW[g][0]);
                aW[g][1] = MFMA(ax[1][ks], b, aW[g][1]);
            }
        }
        // Phase Ub (K=256 over hcat) + Uu (K=128 over h_l)
        {
            bf16x8 ah[2][8];
#pragma unroll
            for (int mt = 0; mt < 2; ++mt)
#pragma unroll
            for (int ks = 0; ks < 8; ++ks)
                ah[mt][ks] = *(const bf16x8*)&hs[mbase + mt * 16 + l16][ks * 32 + quad * 8];
#pragma unroll
            for (int g = 0; g < 5; ++g)
#pragma unroll
            for (int ks = 0; ks < 8; ++ks) {
                bf16x8 b = *(const bf16x8*)(wb + UBB + ((((g * 8 + jc) * 8) + ks) << 9) + lane * 8);
                aB[g][0] = MFMA(ah[0][ks], b, aB[g][0]);
                aB[g][1] = MFMA(ah[1][ks], b, aB[g][1]);
            }
#pragma unroll
            for (int g = 0; g < 4; ++g)
#pragma unroll
            for (int ks = 0; ks < 4; ++ks) {
                bf16x8 b = *(const bf16x8*)(wb + UUB + ((((g * 8 + jc) * 4) + ks) << 9) + lane * 8);
                aU[g][0] = MFMA(ah[0][ks], b, aU[g][0]);
                aU[g][1] = MFMA(ah[1][ks], b, aU[g][1]);
            }
        }
        // Epilogue for this j-chunk
        int j = jc * 16 + l16;
        float4 bw = ((const float4*)(bias + BW4))[j];
        float4 bb = ((const float4*)(bias + BUB4))[j];
        float  b1 = (bias + BUB1)[j];
        float4 bu = ((const float4*)(bias + BUU4))[j];
#pragma unroll
        for (int mt = 0; mt < 2; ++mt)
#pragma unroll
        for (int r = 0; r < 4; ++r) {
            int ml = mbase + mt * 16 + quad * 4 + r;
            int p = p0 + ml;
            bool val = (p < Mtot);
            int pc = val ? p : (Mtot - 1);
            int bl = pc >> lvl, i = pc - (bl << lvl);
            bool bin = (ar[ml] == 1);
            float w0 = aW[0][mt][r] + bw.x;
            float w1 = aW[1][mt][r] + bw.y;
            float w2 = aW[2][mt][r] + bw.z;
            float w3 = aW[3][mt][r] + bw.w;
            float pi, pf, po, pu;
            if (bin) {
                pi = w0 + aB[0][mt][r] + bb.x;
                pf = w1 + aB[1][mt][r] + bb.y;
                po = w2 + aB[3][mt][r] + bb.w;
                pu = w3 + aB[4][mt][r] + b1;
            } else {
                pi = w0 + aU[0][mt][r] + bu.x;
                pf = w1 + aU[1][mt][r] + bu.y;
                po = w2 + aU[2][mt][r] + bu.z;
                pu = w3 + aU[3][mt][r] + bu.w;
            }
            float cl = 0.f, cr = 0.f, frv = 0.f;
            if (!leafchild) {
                cl = cChild[((long)bl * ccnt + 2 * i) * 128 + j];
                if (bin) cr = cChild[((long)bl * ccnt + 2 * i + 1) * 128 + j];
            }
            if (bin) frv = sigm(w1 + aB[2][mt][r] + bb.z);
            float ig = sigm(pi), fg = sigm(pf), og = sigm(po), ug = tanh_(pu);
            float c = ig * ug + fg * cl + frv * cr;
            float h = og * tanh_(c);
            if (val) {
                if (isRoot) {
                    rootH[(long)(treeOff + bl) * 128 + j] = h;
                    rootC[(long)(treeOff + bl) * 128 + j] = c;
                } else {
                    hOut[((long)bl * cnt + i) * 128 + j] = f2s(h);
                    cOut[((long)bl * cnt + i) * 128 + j] = c;
                }
            }
        }
    }
}

// ---- output: rootH/rootC fp32 -> d_out (bf16 or fp32) ----
__global__ __launch_bounds__(256) void out_kernel(const float* ws, void* out)
{
    const int isbf = ((const int*)ws)[0];
    const float* rootH = ws + OFF_ROOT;
    const float* rootC = rootH + 32768;
    int t = blockIdx.x * 256 + threadIdx.x;
    float h = rootH[t], c = rootC[t];
    if (isbf) {
        ((__hip_bfloat16*)out)[t]         = __float2bfloat16(h);
        ((__hip_bfloat16*)out)[32768 + t] = __float2bfloat16(c);
    } else {
        ((float*)out)[t]         = h;
        ((float*)out)[32768 + t] = c;
    }
}

extern "C" void kernel_launch(void* const* d_in, const int* in_sizes, int n_in,
                              void* d_out, int out_size, void* d_ws, size_t ws_size,
                              hipStream_t stream)
{
    const int* tokens = (const int*)d_in[0];
    const int* arity  = (const int*)d_in[1];
    const void* emb   = d_in[2];
    const void* W     = d_in[3];
    const void* bW    = d_in[4];
    const void* Ubin  = d_in[5];
    const void* bUbin = d_in[6];
    const void* Uun   = d_in[7];
    const void* bUun  = d_in[8];

    float* ws = (float*)d_ws;

    int Bc = 256;
    while (Bc > 1 && (size_t)(OFF_CHUNK + Bc * PER_TREE) * 4 > ws_size) Bc >>= 1;
    const int nCh = 256 / Bc;

    detect_kernel<<<1, 64, 0, stream>>>(W, ws);
    repack_mfma<<<128, 256, 0, stream>>>(W, bW, Ubin, bUbin, Uun, bUun, ws);

    short* Ha = (short*)(ws + OFF_CHUNK);          // leaves + even-level h (bf16)
    short* Hb = Ha + (long)Bc * 32768;             // odd-level h (bf16)
    float* Ca = (float*)(Hb + (long)Bc * 16384);   // even-level c (fp32)
    float* Cb = Ca + (long)Bc * 8192;              // odd-level c (fp32)
    float* rootH = ws + OFF_ROOT;
    float* rootC = rootH + 32768;

    for (int cidx = 0; cidx < nCh; ++cidx) {
        int toff = cidx * Bc;
        leaf_mfma<<<Bc * 4, 256, 0, stream>>>(tokens, emb, ws, Ha, toff);
        for (int l = 7; l >= 0; --l) {
            int M = Bc << l;
            int nb = (M + 63) / 64;
            const short* hC = (l & 1) ? Ha : Hb;   // children = level l+1 outputs
            const float* cC = (l & 1) ? Ca : Cb;
            short* hO = (l & 1) ? Hb : Ha;
            float* cO = (l & 1) ? Cb : Ca;
            int lc = (l == 7) ? 1 : 0;
            int isRoot = (l == 0) ? 1 : 0;
            level_mfma<<<nb, 256, 0, stream>>>(tokens, arity, emb, ws, hC, cC, hO, cO,
                                               rootH, rootC, l, toff, lc, isRoot, M);
        }
    }
    out_kernel<<<128, 256, 0, stream>>>(ws, d_out);
}

// Round 4
// 327.369 us; speedup vs baseline: 2.3882x; 1.6101x over previous
//
#include <hip/hip_runtime.h>
#include <hip/hip_bf16.h>

#define NTOK 511
#define NINT 255

typedef unsigned short u16;
typedef __attribute__((ext_vector_type(8))) short bf16x8;
typedef __attribute__((ext_vector_type(4))) float f32x4;

// ---- workspace layout (float offsets) ----
constexpr int OFF_FLAG = 0;                 // [0] dtype flag
constexpr int OFF_WB   = 4;                 // bf16 weight region
// bf16-element offsets inside weight region (jc-major, frag-linear):
//   per jc (72 frags x 512): f 0..15 = Wx(g=f>>2,ks=f&3), 16..31 = Uu, 32..71 = Ub(g=(f-32)>>3,ks=&7)
constexpr int W3B = 294912;                 // leaf W3: [jc][ks] 8x4x512 = 16384
constexpr int WB_ELEMS = 311296;
constexpr int OFF_BIAS = OFF_WB + WB_ELEMS / 2;   // fp32 biases
constexpr int BW4 = 0, BUB4 = 512, BUB1 = 1024, BUU4 = 1152, B3 = 1664;
constexpr int BIAS_FLOATS = 1792;
constexpr int OFF_ROOT  = OFF_BIAS + BIAS_FLOATS;   // rootH 32768 + rootC 32768 (fp32)
constexpr int OFF_CHUNK = OFF_ROOT + 65536;
constexpr long PER_TREE = 49152;            // floats: Ha bf16 + Hb bf16 + Ca f32 + Cb f32

__device__ __forceinline__ float bf2f(__hip_bfloat16 v) { return __bfloat162float(v); }
__device__ __forceinline__ short f2s(float f) {
    __hip_bfloat16 b = __float2bfloat16(f);
    return *reinterpret_cast<short*>(&b);
}
__device__ __forceinline__ float sigm(float x) { return 1.0f / (1.0f + __expf(-x)); }
__device__ __forceinline__ float tanh_(float x) { return 1.0f - 2.0f / (__expf(2.0f * x) + 1.0f); }

__device__ __forceinline__ float ldf(const void* p, long idx, int isbf) {
    return isbf ? bf2f(((const __hip_bfloat16*)p)[idx]) : ((const float*)p)[idx];
}

// A-fragment load (8 contiguous elems) from bf16 or fp32 source
__device__ __forceinline__ bf16x8 ldA(const void* p, long idx, int isbf) {
    if (isbf) return *(const bf16x8*)((const short*)p + idx);
    const float* f = (const float*)p + idx;
    float4 a = *(const float4*)f, b = *(const float4*)(f + 4);
    bf16x8 r;
    r[0] = f2s(a.x); r[1] = f2s(a.y); r[2] = f2s(a.z); r[3] = f2s(a.w);
    r[4] = f2s(b.x); r[5] = f2s(b.y); r[6] = f2s(b.z); r[7] = f2s(b.w);
    return r;
}

// async global->LDS 16B (wave-uniform base + lane*16 pattern)
typedef const __attribute__((address_space(1))) unsigned int* gp1_t;
typedef __attribute__((address_space(3))) unsigned int* lp3_t;
__device__ __forceinline__ void stage16(const void* g, void* l) {
    __builtin_amdgcn_global_load_lds((gp1_t)g, (lp3_t)l, 16, 0, 0);
}

// ---- dtype detection ----
__global__ void detect_kernel(const void* W, float* ws) {
    if (threadIdx.x == 0 && blockIdx.x == 0) {
        const u16* u = (const u16*)W;
        int cnt = 0;
        for (int i = 0; i < 128; i += 2) {
            u16 x = u[i];
            int ex = (x >> 7) & 0xff;
            if (x == 0 || (ex >= 96 && ex <= 127)) cnt++;
        }
        ((int*)ws)[0] = (cnt >= 48) ? 1 : 0;
    }
}

// ---- repack: raw weights -> bf16 jc-major frag-linear + fp32 biases ----
__global__ __launch_bounds__(256) void repack_mfma(
    const void* W, const void* bW, const void* Ubin, const void* bUbin,
    const void* Uun, const void* bUun, float* ws)
{
    const int isbf = ((const int*)ws)[0];
    short* wb = (short*)(ws + OFF_WB);
    float* bias = ws + OFF_BIAS;
    int tid = blockIdx.x * blockDim.x + threadIdx.x;
    int nth = gridDim.x * blockDim.x;

    for (int idx = tid; idx < 294912; idx += nth) {
        int e = idx & 511, fjc = idx >> 9;
        int jc = fjc / 72, f = fjc - jc * 72;
        int lane = e >> 3, id8 = e & 7;
        int j = jc * 16 + (lane & 15);
        float v;
        if (f < 16) {
            int g = f >> 2, ks = f & 3;
            int k = ks * 32 + (lane >> 4) * 8 + id8;
            v = ldf(W, (long)g * 16384 + k * 128 + j, isbf);
        } else if (f < 32) {
            int fu = f - 16; int g = fu >> 2, ks = fu & 3;
            int k = ks * 32 + (lane >> 4) * 8 + id8;
            v = ldf(Uun, (long)g * 16384 + k * 128 + j, isbf);
        } else {
            int fb = f - 32; int g = fb >> 3, ks = fb & 7;
            int k = ks * 32 + (lane >> 4) * 8 + id8;
            v = ldf(Ubin, (long)g * 32768 + k * 128 + j, isbf);
        }
        wb[idx] = f2s(v);
    }
    for (int idx = tid; idx < 16384; idx += nth) {
        int e = idx & 511, frag = idx >> 9;
        int jc = frag >> 2, ks = frag & 3;
        int lane = e >> 3, id8 = e & 7;
        int k = ks * 32 + (lane >> 4) * 8 + id8;
        int j = jc * 16 + (lane & 15);
        wb[W3B + idx] = f2s(ldf(W, (long)3 * 16384 + k * 128 + j, isbf));
    }
    for (int j = tid; j < 128; j += nth) {
        float4 b;
        b.x = ldf(bW, 0 * 128 + j, isbf); b.y = ldf(bW, 1 * 128 + j, isbf);
        b.z = ldf(bW, 2 * 128 + j, isbf); b.w = ldf(bW, 3 * 128 + j, isbf);
        ((float4*)(bias + BW4))[j] = b;
        float4 bb;
        bb.x = ldf(bUbin, 0 * 128 + j, isbf); bb.y = ldf(bUbin, 1 * 128 + j, isbf);
        bb.z = ldf(bUbin, 2 * 128 + j, isbf); bb.w = ldf(bUbin, 3 * 128 + j, isbf);
        ((float4*)(bias + BUB4))[j] = bb;
        (bias + BUB1)[j] = ldf(bUbin, 4 * 128 + j, isbf);
        float4 bu;
        bu.x = ldf(bUun, 0 * 128 + j, isbf); bu.y = ldf(bUun, 1 * 128 + j, isbf);
        bu.z = ldf(bUun, 2 * 128 + j, isbf); bu.w = ldf(bUun, 3 * 128 + j, isbf);
        ((float4*)(bias + BUU4))[j] = bu;
        (bias + B3)[j] = ldf(bW, 3 * 128 + j, isbf);
    }
}

#define MFMA(A, B, C) __builtin_amdgcn_mfma_f32_16x16x32_bf16(A, B, C, 0, 0, 0)

// ---- leaf: h = tanh(x @ W3 + b3); 128 leaves/block, W3 staged in LDS ----
__global__ __launch_bounds__(256, 2) void leaf_mfma(
    const int* __restrict__ tokens, const void* emb, const float* __restrict__ ws,
    short* __restrict__ hOut, int treeOff, int Mtot)
{
    __shared__ short Bs[16384];        // 32 KB: whole W3 region
    __shared__ short hst[128 * 128];   // 32 KB: h output staging
    __shared__ int tok[128];

    const int t = threadIdx.x;
    const int isbf = ((const int*)ws)[0];
    const int p0 = blockIdx.x * 128;
    const short* wb = (const short*)(ws + OFF_WB);
    const float* bias = ws + OFF_BIAS;

    if (t < 128) {
        int p = p0 + t; if (p >= Mtot) p = Mtot - 1;
        int bl = p >> 8, i = p & 255;
        tok[t] = tokens[(long)(treeOff + bl) * NTOK + 255 + i];
    }
    __syncthreads();

    // stage W3 (32 KB)
#pragma unroll
    for (int it = 0; it < 8; ++it) {
        int off = (it * 256 + t) * 8;
        stage16(wb + W3B + off, &Bs[off]);
    }

    const int wv = t >> 6, lane = t & 63, quad = lane >> 4, l16 = lane & 15;
    // A-fragments: 2 m-subtiles per wave
    bf16x8 ax[2][4];
#pragma unroll
    for (int mt = 0; mt < 2; ++mt) {
        int row = wv * 32 + mt * 16 + l16;
#pragma unroll
        for (int ks = 0; ks < 4; ++ks)
            ax[mt][ks] = ldA(emb, (long)tok[row] * 128 + ks * 32 + quad * 8, isbf);
    }
    __syncthreads();   // staging + A loads complete

    for (int jc = 0; jc < 8; ++jc) {
        f32x4 acc0 = {0,0,0,0}, acc1 = {0,0,0,0};
#pragma unroll
        for (int ks = 0; ks < 4; ++ks) {
            bf16x8 b = *(const bf16x8*)&Bs[((jc << 2) | ks) * 512 + lane * 8];
            acc0 = MFMA(ax[0][ks], b, acc0);
            acc1 = MFMA(ax[1][ks], b, acc1);
        }
        int j = jc * 16 + l16;
        float b3v = (bias + B3)[j];
#pragma unroll
        for (int mt = 0; mt < 2; ++mt)
#pragma unroll
        for (int r = 0; r < 4; ++r) {
            float v = (mt == 0 ? acc0[r] : acc1[r]) + b3v;
            int row = wv * 32 + mt * 16 + quad * 4 + r;
            hst[row * 128 + j] = f2s(tanh_(v));
        }
    }
    __syncthreads();
    // coalesced writeout
#pragma unroll
    for (int it = 0; it < 8; ++it) {
        int q = it * 256 + t;
        int row = q >> 4, cc = q & 15;
        int p = p0 + row;
        if (p < Mtot)
            *(uint4*)&hOut[(long)p * 128 + cc * 8] = *(const uint4*)&hst[row * 128 + cc * 8];
    }
}

// ---- internal level: LDS-staged weights, A in registers, M=128/block, j-split ----
__global__ __launch_bounds__(256, 2) void level_mfma(
    const int* __restrict__ tokens, const int* __restrict__ arity, const void* emb,
    const float* __restrict__ ws, const short* __restrict__ hChild,
    const float* __restrict__ cChild, short* __restrict__ hOut, float* __restrict__ cOut,
    float* __restrict__ rootH, float* __restrict__ rootC,
    int lvl, int treeOff, int leafchild, int isRoot, int Mtot, int js, int jcCount)
{
    __shared__ short Bs[18432];        // 36 KB stage buffer (36 frags)
    __shared__ short hst[128 * 128];   // up to 32 KB h staging
    __shared__ int tok[128];
    __shared__ int ar[128];

    const int t = threadIdx.x;
    const int isbf = ((const int*)ws)[0];
    const int mb = blockIdx.x / js, jsx = blockIdx.x % js;
    const int jcLo = jsx * jcCount;
    const int p0 = mb * 128;
    const int cnt = 1 << lvl, ccnt = cnt << 1, o2 = cnt - 1;
    const short* wb = (const short*)(ws + OFF_WB);
    const float* bias = ws + OFF_BIAS;

    if (t < 128) {
        int p = p0 + t; if (p >= Mtot) p = Mtot - 1;
        int bl = p >> lvl, i = p - (bl << lvl);
        tok[t] = tokens[(long)(treeOff + bl) * NTOK + o2 + i];
        ar[t]  = arity[(long)(treeOff + bl) * NINT + o2 + i];
    }
    __syncthreads();

    const int wv = t >> 6, lane = t & 63, quad = lane >> 4, l16 = lane & 15;

    // A-fragments in registers: 2 m-subtiles (32 nodes) per wave
    bf16x8 ax[2][4], ah[2][8];
#pragma unroll
    for (int mt = 0; mt < 2; ++mt) {
        int row = wv * 32 + mt * 16 + l16;
        int p = p0 + row; if (p >= Mtot) p = Mtot - 1;
        int bl = p >> lvl, i = p - (bl << lvl);
        long lrow = (long)bl * ccnt + 2 * i;
#pragma unroll
        for (int ks = 0; ks < 4; ++ks) {
            ax[mt][ks] = ldA(emb, (long)tok[row] * 128 + ks * 32 + quad * 8, isbf);
            ah[mt][ks] = *(const bf16x8*)(hChild + lrow * 128 + ks * 32 + quad * 8);
            ah[mt][ks + 4] = *(const bf16x8*)(hChild + (lrow + 1) * 128 + ks * 32 + quad * 8);
        }
    }

    for (int jx = 0; jx < jcCount; ++jx) {
        int jc = jcLo + jx;
        const short* wsrc = wb + (long)jc * 72 * 512;

        // ---- phase 0: frags 0..35 (Wx 16, Uu 16, Ub g0 4) ----
#pragma unroll
        for (int it = 0; it < 9; ++it) {
            int off = (it * 256 + t) * 8;
            stage16(wsrc + off, &Bs[off]);
        }
        __syncthreads();

        f32x4 aW[4][2], aU[4][2], aB[5][2];
#pragma unroll
        for (int g = 0; g < 4; ++g) { aW[g][0] = {0,0,0,0}; aW[g][1] = {0,0,0,0}; }
#pragma unroll
        for (int g = 0; g < 4; ++g) { aU[g][0] = {0,0,0,0}; aU[g][1] = {0,0,0,0}; }
#pragma unroll
        for (int g = 0; g < 5; ++g) { aB[g][0] = {0,0,0,0}; aB[g][1] = {0,0,0,0}; }

#pragma unroll
        for (int f = 0; f < 16; ++f) {
            bf16x8 b = *(const bf16x8*)&Bs[f * 512 + lane * 8];
            aW[f >> 2][0] = MFMA(ax[0][f & 3], b, aW[f >> 2][0]);
            aW[f >> 2][1] = MFMA(ax[1][f & 3], b, aW[f >> 2][1]);
        }
#pragma unroll
        for (int f = 16; f < 32; ++f) {
            bf16x8 b = *(const bf16x8*)&Bs[f * 512 + lane * 8];
            aU[(f - 16) >> 2][0] = MFMA(ah[0][(f - 16) & 3], b, aU[(f - 16) >> 2][0]);
            aU[(f - 16) >> 2][1] = MFMA(ah[1][(f - 16) & 3], b, aU[(f - 16) >> 2][1]);
        }
#pragma unroll
        for (int f = 32; f < 36; ++f) {
            bf16x8 b = *(const bf16x8*)&Bs[f * 512 + lane * 8];
            aB[0][0] = MFMA(ah[0][f - 32], b, aB[0][0]);
            aB[0][1] = MFMA(ah[1][f - 32], b, aB[0][1]);
        }
        __syncthreads();

        // ---- phase 1: frags 36..71 (Ub rest) ----
#pragma unroll
        for (int it = 0; it < 9; ++it) {
            int off = (it * 256 + t) * 8;
            stage16(wsrc + 36 * 512 + off, &Bs[off]);
        }
        __syncthreads();

#pragma unroll
        for (int f = 36; f < 72; ++f) {
            int fb = f - 32, g = fb >> 3, ks = fb & 7;
            bf16x8 b = *(const bf16x8*)&Bs[(f - 36) * 512 + lane * 8];
            aB[g][0] = MFMA(ah[0][ks], b, aB[g][0]);
            aB[g][1] = MFMA(ah[1][ks], b, aB[g][1]);
        }

        // ---- epilogue for this jc ----
        int j = jc * 16 + l16;
        float4 bw = ((const float4*)(bias + BW4))[j];
        float4 bb = ((const float4*)(bias + BUB4))[j];
        float  b1 = (bias + BUB1)[j];
        float4 bu = ((const float4*)(bias + BUU4))[j];
#pragma unroll
        for (int mt = 0; mt < 2; ++mt)
#pragma unroll
        for (int r = 0; r < 4; ++r) {
            int ml = wv * 32 + mt * 16 + quad * 4 + r;
            int p = p0 + ml;
            bool val = (p < Mtot);
            int pc = val ? p : (Mtot - 1);
            int bl = pc >> lvl, i = pc - (bl << lvl);
            bool bin = (ar[ml] == 1);
            float w0 = aW[0][mt][r] + bw.x;
            float w1 = aW[1][mt][r] + bw.y;
            float w2 = aW[2][mt][r] + bw.z;
            float w3 = aW[3][mt][r] + bw.w;
            float pi, pf, po, pu;
            if (bin) {
                pi = w0 + aB[0][mt][r] + bb.x;
                pf = w1 + aB[1][mt][r] + bb.y;
                po = w2 + aB[3][mt][r] + bb.w;
                pu = w3 + aB[4][mt][r] + b1;
            } else {
                pi = w0 + aU[0][mt][r] + bu.x;
                pf = w1 + aU[1][mt][r] + bu.y;
                po = w2 + aU[2][mt][r] + bu.z;
                pu = w3 + aU[3][mt][r] + bu.w;
            }
            float cl = 0.f, cr = 0.f, frv = 0.f;
            if (!leafchild) {
                cl = cChild[((long)bl * ccnt + 2 * i) * 128 + j];
                if (bin) cr = cChild[((long)bl * ccnt + 2 * i + 1) * 128 + j];
            }
            if (bin) frv = sigm(w1 + aB[2][mt][r] + bb.z);
            float ig = sigm(pi), fg = sigm(pf), og = sigm(po), ug = tanh_(pu);
            float c = ig * ug + fg * cl + frv * cr;
            float h = og * tanh_(c);
            if (val) {
                if (isRoot) {
                    rootH[(long)(treeOff + bl) * 128 + j] = h;
                    rootC[(long)(treeOff + bl) * 128 + j] = c;
                } else {
                    cOut[((long)bl * cnt + i) * 128 + j] = c;
                    hst[ml * (jcCount * 16) + jx * 16 + l16] = f2s(h);
                }
            } else if (!isRoot) {
                hst[ml * (jcCount * 16) + jx * 16 + l16] = 0;
            }
        }
        __syncthreads();   // protect Bs for next jc + hst coherence
    }

    // ---- coalesced h writeout ----
    if (!isRoot) {
        int ncols = jcCount * 16;
        int chunks = 128 * ncols / 8;
        for (int q = t; q < chunks; q += 256) {
            int c8 = ncols / 8;
            int row = q / c8, cc = q - row * c8;
            int p = p0 + row;
            if (p < Mtot) {
                int bl = p >> lvl, i = p - (bl << lvl);
                *(uint4*)&hOut[((long)bl * cnt + i) * 128 + jcLo * 16 + cc * 8] =
                    *(const uint4*)&hst[row * ncols + cc * 8];
            }
        }
    }
}

// ---- output: rootH/rootC fp32 -> d_out ----
__global__ __launch_bounds__(256) void out_kernel(const float* ws, void* out)
{
    const int isbf = ((const int*)ws)[0];
    const float* rootH = ws + OFF_ROOT;
    const float* rootC = rootH + 32768;
    int t = blockIdx.x * 256 + threadIdx.x;
    float h = rootH[t], c = rootC[t];
    if (isbf) {
        ((__hip_bfloat16*)out)[t]         = __float2bfloat16(h);
        ((__hip_bfloat16*)out)[32768 + t] = __float2bfloat16(c);
    } else {
        ((float*)out)[t]         = h;
        ((float*)out)[32768 + t] = c;
    }
}

extern "C" void kernel_launch(void* const* d_in, const int* in_sizes, int n_in,
                              void* d_out, int out_size, void* d_ws, size_t ws_size,
                              hipStream_t stream)
{
    const int* tokens = (const int*)d_in[0];
    const int* arity  = (const int*)d_in[1];
    const void* emb   = d_in[2];
    const void* W     = d_in[3];
    const void* bW    = d_in[4];
    const void* Ubin  = d_in[5];
    const void* bUbin = d_in[6];
    const void* Uun   = d_in[7];
    const void* bUun  = d_in[8];

    float* ws = (float*)d_ws;

    int Bc = 256;
    while (Bc > 1 && (size_t)(OFF_CHUNK + Bc * PER_TREE) * 4 > ws_size) Bc >>= 1;
    const int nCh = 256 / Bc;

    detect_kernel<<<1, 64, 0, stream>>>(W, ws);
    repack_mfma<<<128, 256, 0, stream>>>(W, bW, Ubin, bUbin, Uun, bUun, ws);

    short* Ha = (short*)(ws + OFF_CHUNK);          // leaves + even-level h (bf16)
    short* Hb = Ha + (long)Bc * 32768;             // odd-level h (bf16)
    float* Ca = (float*)(Hb + (long)Bc * 16384);   // even-level c (fp32)
    float* Cb = Ca + (long)Bc * 8192;              // odd-level c (fp32)
    float* rootH = ws + OFF_ROOT;
    float* rootC = rootH + 32768;

    for (int cidx = 0; cidx < nCh; ++cidx) {
        int toff = cidx * Bc;
        {
            int Mleaf = Bc * 256;
            int nb = (Mleaf + 127) / 128;
            leaf_mfma<<<nb, 256, 0, stream>>>(tokens, emb, ws, Ha, toff, Mleaf);
        }
        for (int l = 7; l >= 0; --l) {
            int M = Bc << l;
            int Mb = (M + 127) / 128;
            int js = 1;
            while (js < 8 && Mb * js * 2 <= 512) js <<= 1;
            int jcCount = 8 / js;
            const short* hC = (l & 1) ? Ha : Hb;
            const float* cC = (l & 1) ? Ca : Cb;
            short* hO = (l & 1) ? Hb : Ha;
            float* cO = (l & 1) ? Cb : Ca;
            int lc = (l == 7) ? 1 : 0;
            int isRoot = (l == 0) ? 1 : 0;
            level_mfma<<<Mb * js, 256, 0, stream>>>(tokens, arity, emb, ws, hC, cC, hO, cO,
                                                    rootH, rootC, l, toff, lc, isRoot, M, js, jcCount);
        }
    }
    out_kernel<<<128, 256, 0, stream>>>(ws, d_out);
}